// Round 12
// baseline (167.837 us; speedup 1.0000x reference)
//
#include <hip/hip_runtime.h>
#include <cstddef>

#define TB    512
#define NB    128
#define NSTEP 10
#define SENTV 0xFFFFFFFFFFFFFFFFULL
// Problem constants: N=4096, E=65536 (=N*16, uniform degree 16, row-major
// sorted so out-edges of node i are slots [16i,16i+16)), Eu=32768.
// Slot scheme: em slot g (g=16i+t) holds the message on edge rev[g]=(j->i).
// We propagate u = hidden + lnZ; hidden recovered as u - lse(u) at readout.
// R13 (kept): SELF-ANNOUNCING DATA. Write-once sentinel slots (0xFF memset),
// consumers poll the datum's own bits != sentinel. No barriers/flags/fences.
// R15 (kept): push-based u delivery, own-slot coalesced polls. Producers
// (jsC/em/uFin/uIn stores) are BYTE-IDENTICAL to the R15 kernel that passed.
// R18 (this round; consumer-side only, after R16/R17 record-epilogue failed
// to run twice): (a) batched epilogue poll — all 5 epilogue addresses come
// from read-only inputs (u2e/ru/cu/rev), so issue 5 independent ldU's and
// re-poll only still-sentinel slots: ONE MALL round-trip instead of 5
// sequential ones. (b) fAIn exchange deleted: rsj computed locally (16
// scattered J reads, proven in R11) -> C needs no cross-block data, jsC
// publishes BEFORE the MLP, one fewer serial MALL round in setup.

__device__ __forceinline__ float lse2(float a, float b) {
    return fmaxf(a, b) + __logf(1.0f + __expf(-fabsf(a - b)));
}

// agent-scope write-through / cache-bypass 8B accessors
__device__ __forceinline__ void stA(float2* p, float2 v) {
    union { float2 f; unsigned long long u; } x; x.f = v;
    __hip_atomic_store((unsigned long long*)p, x.u,
                       __ATOMIC_RELAXED, __HIP_MEMORY_SCOPE_AGENT);
}
__device__ __forceinline__ unsigned long long ldU(const float2* p) {
    return __hip_atomic_load((const unsigned long long*)p,
                             __ATOMIC_RELAXED, __HIP_MEMORY_SCOPE_AGENT);
}
// poll the datum itself until its bits != sentinel; returns the value
__device__ __forceinline__ float2 pollLd(const float2* p) {
    union { float2 f; unsigned long long u; } x;
    x.u = ldU(p);
    while (x.u == SENTV) {
        __builtin_amdgcn_s_sleep(1);
        x.u = ldU(p);
    }
    return x.f;
}

struct KParams {
    const float *J, *bias, *gat_W, *gat_a, *W1, *b1, *W2, *b2, *W3, *b3;
    const int *col, *rev, *ru, *cu, *u2e;
    int N, Eu;
    float2 *jsC, *em, *uIn, *uFin;   // uIn: NSTEP x E; all sentinel-init
    float  *ci_out, *dom_out, *ent;
    float2* ro_out;
    float4* rp_out;
    float*  cij_out;
};

__global__ __launch_bounds__(TB) void k_fused(KParams p) {
    __shared__ float4 sW2T[64 * 17];          // [o][hh]: W2 col o, 4-packed
    __shared__ float  sh1[TB / 16][68];       // h1 per node, 16B-aligned rows
    __shared__ float  red[TB / 64];

    const int tidb = threadIdx.x;
    const int g = blockIdx.x * TB + tidb;
    const int i = g >> 4, t = g & 15;
    const int lane = tidb & 63;
    const int E = p.N * 16;

    // ---------------- setup ------------------------------------------------
    // stage W2 transposed+packed: sW2T[o*17+hh] = W2[4hh..4hh+3][o]
    for (int idx = tidb; idx < 64 * 16; idx += TB) {
        const int o = idx >> 4, hh = idx & 15;
        sW2T[o * 17 + hh] = make_float4(
            p.W2[(4 * hh + 0) * 64 + o], p.W2[(4 * hh + 1) * 64 + o],
            p.W2[(4 * hh + 2) * 64 + o], p.W2[(4 * hh + 3) * 64 + o]);
    }
    if (g < 3) {  // zero entropy accumulators early; adds happen >>later
        __hip_atomic_store((int*)&p.ent[g], 0,
                           __ATOMIC_RELAXED, __HIP_MEMORY_SCOPE_AGENT);
    }

    const int j  = p.col[g];
    const int rg = p.rev[g];
    const float* Jri = p.J + (size_t)i * (size_t)p.N;
    const float* Jrj = p.J + (size_t)j * (size_t)p.N;
    const int* coli = p.col + 16 * i;
    const int* colj = p.col + 16 * j;
    const float Jv = Jri[j];

    // Row-sums computed locally, identical sequential order on both rows.
    float rs = 0.0f, rsj = 0.0f;
    #pragma unroll 4
    for (int tt = 0; tt < 16; ++tt) rs  += Jri[coli[tt]];
    #pragma unroll 4
    for (int tt = 0; tt < 16; ++tt) rsj += Jrj[colj[tt]];

    const float bi = p.bias[i], bj = p.bias[j];

    // gat_W^T @ gat_a: 8 dot-products of length 64, 64-lane parallel.
    float s8 = 0.0f;
    {
        const int d8 = lane >> 3, c8 = lane & 7;
        const int kk = d8 & 3;
        const float* ga = p.gat_a + ((d8 < 4) ? 0 : 64);
        #pragma unroll
        for (int h = 0; h < 8; ++h)
            s8 += p.gat_W[kk * 64 + 8 * c8 + h] * ga[8 * c8 + h];
        s8 += __shfl_xor(s8, 1); s8 += __shfl_xor(s8, 2); s8 += __shfl_xor(s8, 4);
    }
    const float w10 = __shfl(s8, 0),  w11 = __shfl(s8, 8);
    const float w12 = __shfl(s8, 16), w13 = __shfl(s8, 24);
    const float w20 = __shfl(s8, 32), w21 = __shfl(s8, 40);
    const float w22 = __shfl(s8, 48), w23 = __shfl(s8, 56);
    const float fd = 16.0f;
    const float f1i = -bi * w10 + bi * w11 + fd * w12 + rs  * w13;
    const float f2i = -bi * w20 + bi * w21 + fd * w22 + rs  * w23;
    const float f1j = -bj * w10 + bj * w11 + fd * w12 + rsj * w13;
    const float f2j = -bj * w20 + bj * w21 + fd * w22 + rsj * w23;

    float x1 = f1i + f2j; x1 = (x1 > 0.0f) ? x1 : 0.2f * x1;
    float x2 = f1j + f2i; x2 = (x2 > 0.0f) ? x2 : 0.2f * x2;
    const float C  = 0.5f * (__expf(x1) + __expf(x2));   // symmetric g <-> rev[g]
    const float js = Jv / C;
    stA(&p.jsC[g], make_float2(js, C));       // publish EARLY (pre-MLP)

    float sc = C;
    sc += __shfl_xor(sc, 1); sc += __shfl_xor(sc, 2);
    sc += __shfl_xor(sc, 4); sc += __shfl_xor(sc, 8);

    // Ci readout MLP (per node, 16 threads per node)
    const int nib = tidb >> 4;
    #pragma unroll
    for (int m = 0; m < 4; ++m) {
        int h = t + 16 * m;
        float a = -bi * p.W1[h] + bi * p.W1[64 + h] + fd * p.W1[128 + h]
                + rs * p.W1[192 + h] + p.b1[h];
        sh1[nib][h] = fmaxf(a, 0.0f);
    }
    __syncthreads();                          // sW2T + sh1 staged
    float4 hv[16];                            // node's h1, hoisted
    {
        const float4* hrow = (const float4*)&sh1[nib][0];
        #pragma unroll
        for (int hh = 0; hh < 16; ++hh) hv[hh] = hrow[hh];
    }
    float civ = 0.0f;
    #pragma unroll
    for (int m = 0; m < 4; ++m) {
        const int o = t + 16 * m;
        const float4* wrow = &sW2T[o * 17];
        float acc = p.b2[o];
        #pragma unroll
        for (int hh = 0; hh < 16; ++hh) {
            const float4 wv = wrow[hh];
            acc += hv[hh].x * wv.x + hv[hh].y * wv.y
                 + hv[hh].z * wv.z + hv[hh].w * wv.w;
        }
        civ += fmaxf(acc, 0.0f) * p.W3[o];
    }
    civ += __shfl_xor(civ, 1); civ += __shfl_xor(civ, 2);
    civ += __shfl_xor(civ, 4); civ += __shfl_xor(civ, 8);
    const float ci = civ + p.b3[0];

    const float s  = ci + sc;
    const float cl = fmaxf(fabsf(s), 0.1f);
    const float d  = (s > 0.0f) ? cl : ((s < 0.0f) ? -cl : 0.0f);
    const float rd = 1.0f / d;
    const float bs = bi * rd;
    if (t == 0) {
        p.ci_out[i] = ci;                     // outputs (plain stores)
        p.dom_out[i] = d;
    }
    stA(&p.uIn[rg], make_float2(-bs, bs));    // push u^0 to partner (buf 0)

    // prefetch epilogue indices (read-only inputs, independent)
    int eE = 0, eR = 0, eC = 0, eEr = 0;
    if (g < p.Eu) {
        eE = p.u2e[g]; eR = p.ru[g]; eC = p.cu[g];
        eEr = p.rev[eE];
    }

    // ---------------- BP steps: push-delivery, own-slot polls ---------------
    float in0 = 0.0f, in1 = 0.0f;             // msg j->i (slot g)
    float out0 = 0.0f, out1 = 0.0f;           // msg i->j (slot rev[g])
    float ui0 = -bs, ui1 = bs;                // u[i], tracked by every thread
    for (int st = 0; st < NSTEP; ++st) {
        const float2 uj = pollLd(&p.uIn[(size_t)st * E + g]);  // own slot
        // in_new = F(u_j - out_old)
        const float a0 = uj.x - out0, a1 = uj.y - out1;
        const float t0 = fmaxf( js + a0, -js + a1);
        const float t1 = fmaxf(-js + a0,  js + a1);
        const float ls = lse2(t0, t1);
        const float ni0 = C * (t0 - ls), ni1 = C * (t1 - ls);
        const float pu0 = ui0, pu1 = ui1;     // save for out-message
        const float pi0 = in0, pi1 = in1;
        in0 = ni0; in1 = ni1;

        float nm0 = in0, nm1 = in1;           // node's 16 incoming messages
        nm0 += __shfl_xor(nm0, 1); nm1 += __shfl_xor(nm1, 1);
        nm0 += __shfl_xor(nm0, 2); nm1 += __shfl_xor(nm1, 2);
        nm0 += __shfl_xor(nm0, 4); nm1 += __shfl_xor(nm1, 4);
        nm0 += __shfl_xor(nm0, 8); nm1 += __shfl_xor(nm1, 8);
        ui0 = -bs + nm0 * rd; ui1 = bs + nm1 * rd;
        if (st < NSTEP - 1) {
            stA(&p.uIn[(size_t)(st + 1) * E + rg], make_float2(ui0, ui1));
        } else {
            if (t == 0) stA(&p.uFin[i], make_float2(ui0, ui1));
            stA(&p.em[g], make_float2(in0, in1));   // final msgs for epilogue
        }

        // out_new = F(u_i_old - in_old) — off the inter-node critical path
        const float b0 = pu0 - pi0, b1 = pu1 - pi1;
        const float q0 = fmaxf( js + b0, -js + b1);
        const float q1 = fmaxf(-js + b0,  js + b1);
        const float qs = lse2(q0, q1);
        out0 = C * (q0 - qs); out1 = C * (q1 - qs);
    }

    // ---------------- node readout + node entropy ---------------------------
    float nodeC = 0.0f;
    if (t == 0) {
        const float lz = lse2(ui0, ui1);
        const float r0 = __expf(ui0 - lz), r1 = __expf(ui1 - lz);
        p.ro_out[i] = make_float2(r0, r1);
        const float H = -(r0 * __logf(r0 + 1e-16f) + r1 * __logf(r1 + 1e-16f));
        nodeC = ci * H;
    }
    for (int off = 32; off > 0; off >>= 1) nodeC += __shfl_down(nodeC, off);
    {
        const int wv = tidb >> 6;
        if (lane == 0) red[wv] = nodeC;
        __syncthreads();
        if (tidb == 0) {
            float sn = 0.0f;
            #pragma unroll
            for (int w = 0; w < TB / 64; ++w) sn += red[w];
            atomicAdd(&p.ent[0], sn);
            atomicAdd(&p.ent[1], sn);
        }
        __syncthreads();                      // protect red[] reuse below
    }

    // ---------------- epilogue: ONE batched poll round per upper edge -------
    float edgeC = 0.0f;
    if (g < p.Eu) {
        const float2* A0 = &p.jsC[eE];        // {js, C} of edge e
        const float2* A1 = &p.em[eE];         // slot e  = ref em[rev e]
        const float2* A2 = &p.em[eEr];        // slot rev[e] = ref em[e]
        const float2* A3 = &p.uFin[eR];       // final u at node ru
        const float2* A4 = &p.uFin[eC];       // final u at node cu
        union { float2 f; unsigned long long u; } a0, a1, a2, a3, a4;
        a0.u = a1.u = a2.u = a3.u = a4.u = SENTV;
        for (;;) {                            // re-load only pending slots
            if (a0.u == SENTV) a0.u = ldU(A0);
            if (a1.u == SENTV) a1.u = ldU(A1);
            if (a2.u == SENTV) a2.u = ldU(A2);
            if (a3.u == SENTV) a3.u = ldU(A3);
            if (a4.u == SENTV) a4.u = ldU(A4);
            if (a0.u != SENTV && a1.u != SENTV && a2.u != SENTV &&
                a3.u != SENTV && a4.u != SENTV) break;
            __builtin_amdgcn_s_sleep(1);
        }
        const float jse = a0.f.x, Ce = a0.f.y;
        const float2 emr = a1.f;              // ref em[rev e]  (pairs u_r)
        const float2 eme = a2.f;              // ref em[e]      (pairs u_c)
        const float2 ur  = a3.f;
        const float2 uc  = a4.f;
        const float lc = lse2(uc.x, uc.y);
        const float lr = lse2(ur.x, ur.y);
        const float ti0 = (uc.x - lc) - eme.x, ti1 = (uc.y - lc) - eme.y;
        const float tj0 = (ur.x - lr) - emr.x, tj1 = (ur.y - lr) - emr.y;
        const float L00 =  jse + ti0 + tj0;
        const float L01 = -jse + ti1 + tj0;
        const float L10 = -jse + ti0 + tj1;
        const float L11 =  jse + ti1 + tj1;
        const float mL = fmaxf(fmaxf(L00, L01), fmaxf(L10, L11));
        float p00 = __expf(L00 - mL), p01 = __expf(L01 - mL);
        float p10 = __expf(L10 - mL), p11 = __expf(L11 - mL);
        const float inv = 1.0f / (p00 + p01 + p10 + p11);
        p00 *= inv; p01 *= inv; p10 *= inv; p11 *= inv;
        p.rp_out[g] = make_float4(p00, p01, p10, p11);
        p.cij_out[g] = Ce;
        const float H = -(p00 * __logf(p00 + 1e-16f) + p01 * __logf(p01 + 1e-16f)
                        + p10 * __logf(p10 + 1e-16f) + p11 * __logf(p11 + 1e-16f));
        edgeC = Ce * H;
    }
    for (int off = 32; off > 0; off >>= 1) edgeC += __shfl_down(edgeC, off);
    const int wv = tidb >> 6;
    if (lane == 0) red[wv] = edgeC;
    __syncthreads();
    if (tidb == 0) {
        float se = 0.0f;
        #pragma unroll
        for (int w = 0; w < TB / 64; ++w) se += red[w];
        atomicAdd(&p.ent[0], se);
        atomicAdd(&p.ent[2], se);
    }
}

extern "C" void kernel_launch(void* const* d_in, const int* in_sizes, int n_in,
                              void* d_out, int out_size, void* d_ws, size_t ws_size,
                              hipStream_t stream) {
    const int N  = in_sizes[1];
    const int E  = in_sizes[10];
    const int Eu = in_sizes[13];

    float* out = (float*)d_out;
    size_t OFF_RP  = 2 * (size_t)N;
    size_t OFF_ENT = OFF_RP + 4 * (size_t)Eu;

    char* w = (char*)d_ws;
    auto carve = [&](size_t bytes) {
        void* q = (void*)w;
        w += (bytes + 255) & ~(size_t)255;
        return q;
    };

    KParams p;
    p.J     = (const float*)d_in[0];
    p.bias  = (const float*)d_in[1];
    p.gat_W = (const float*)d_in[2];
    p.gat_a = (const float*)d_in[3];
    p.W1    = (const float*)d_in[4];
    p.b1    = (const float*)d_in[5];
    p.W2    = (const float*)d_in[6];
    p.b2    = (const float*)d_in[7];
    p.W3    = (const float*)d_in[8];
    p.b3    = (const float*)d_in[9];
    p.col   = (const int*)d_in[11];
    p.rev   = (const int*)d_in[12];
    p.ru    = (const int*)d_in[13];
    p.cu    = (const int*)d_in[14];
    p.u2e   = (const int*)d_in[15];
    p.N = N; p.Eu = Eu;

    // contiguous sentinel region: jsC | em | uIn(10xE) | uFin
    const size_t szJC = (size_t)E * 8;                 // 512 KB
    const size_t szEM = (size_t)E * 8;                 // 512 KB
    const size_t szUI = (size_t)NSTEP * E * 8;         // 5 MB
    const size_t szUF = (size_t)N * 8;                 // 32 KB
    p.jsC  = (float2*)carve(szJC);
    p.em   = (float2*)carve(szEM);
    p.uIn  = (float2*)carve(szUI);
    p.uFin = (float2*)carve(szUF);

    p.ro_out  = (float2*)out;
    p.rp_out  = (float4*)(out + OFF_RP);
    p.ent     = out + OFF_ENT;
    p.ci_out  = p.ent + 3;
    p.cij_out = p.ci_out + N;
    p.dom_out = p.cij_out + Eu;

    // one memset: sentinel-fill every cross-block buffer (write-once slots)
    hipMemsetAsync(p.jsC, 0xFF, szJC + szEM + szUI + szUF, stream);
    k_fused<<<dim3(NB), dim3(TB), 0, stream>>>(p);
}

// Round 13
// 156.237 us; speedup vs baseline: 1.0742x; 1.0742x over previous
//
#include <hip/hip_runtime.h>
#include <cstddef>

#define TB    512
#define NB    128
#define NSTEP 10
#define SENTV 0xFFFFFFFFFFFFFFFFULL
// Problem constants: N=4096, E=65536 (=N*16, uniform degree 16, row-major
// sorted so out-edges of node i are slots [16i,16i+16)), Eu=32768.
// Slot scheme: em slot g (g=16i+t) holds the message on edge rev[g]=(j->i).
// We propagate u = hidden + lnZ; hidden recovered as u - lse(u) at readout.
// R19 = R13 base (best measured, 40.5us; producers/protocol byte-identical)
// + three low-risk grafts:
//  (1) 64-lane gat_W^T@a reduction (R15-proven): was 8 lanes x 64 serial
//      FMAs on the critical path to fA publish -> now 8 FMAs + 3 shuffles.
//  (2) publish u^{st+1} BEFORE the out-message compute (R14-proven): out
//      only feeds the next step; shortens each inter-node latency round.
//  (3) batched epilogue poll (consumer-side only): 4 independent ldU's per
//      sweep, re-poll only still-sentinel slots -> 1 MALL round-trip
//      instead of 4 sequential ones. jsC still prefetched pre-loop.
// R13 recap: SELF-ANNOUNCING DATA - write-once sentinel slots (0xFF memset),
// consumers poll the datum's own bits != sentinel; no barriers/flags/fences.
// u gets NSTEP+1 buffers (no WAR, nodes free-run); fA exchange published
// EARLY, polled AFTER the MLP (latency hidden); em in registers all steps.

__device__ __forceinline__ float lse2(float a, float b) {
    return fmaxf(a, b) + __logf(1.0f + __expf(-fabsf(a - b)));
}

// agent-scope write-through / cache-bypass 8B accessors
__device__ __forceinline__ void stA(float2* p, float2 v) {
    union { float2 f; unsigned long long u; } x; x.f = v;
    __hip_atomic_store((unsigned long long*)p, x.u,
                       __ATOMIC_RELAXED, __HIP_MEMORY_SCOPE_AGENT);
}
__device__ __forceinline__ unsigned long long ldU(const float2* p) {
    return __hip_atomic_load((const unsigned long long*)p,
                             __ATOMIC_RELAXED, __HIP_MEMORY_SCOPE_AGENT);
}
// poll the datum itself until its bits != sentinel; returns the value
__device__ __forceinline__ float2 pollLd(const float2* p) {
    union { float2 f; unsigned long long u; } x;
    x.u = ldU(p);
    while (x.u == SENTV) {
        __builtin_amdgcn_s_sleep(1);
        x.u = ldU(p);
    }
    return x.f;
}

struct KParams {
    const float *J, *bias, *gat_W, *gat_a, *W1, *b1, *W2, *b2, *W3, *b3;
    const int *col, *rev, *ru, *cu, *u2e;
    int N, Eu;
    float2 *fA, *jsC, *em, *uS;   // uS: (NSTEP+1) x N, all sentinel-init
    float  *ci_out, *dom_out, *ent;
    float2* ro_out;
    float4* rp_out;
    float*  cij_out;
};

__global__ __launch_bounds__(TB) void k_fused(KParams p) {
    __shared__ float sW2[64 * 64];
    __shared__ float sh1[TB / 16][65];
    __shared__ float red[TB / 64];

    const int tidb = threadIdx.x;
    const int g = blockIdx.x * TB + tidb;
    const int i = g >> 4, t = g & 15;
    const int lane = tidb & 63;
    const int N = p.N;

    // ---------------- setup ------------------------------------------------
    for (int k = tidb; k < 64 * 64; k += TB) sW2[k] = p.W2[k];
    if (g < 3) {  // zero entropy accumulators early; adds happen >>later
        __hip_atomic_store((int*)&p.ent[g], 0,
                           __ATOMIC_RELAXED, __HIP_MEMORY_SCOPE_AGENT);
    }

    const int j  = p.col[g];
    const float Jv = p.J[(size_t)i * (size_t)N + (size_t)j];

    float rs = Jv;                            // row-sum of node i (16 nnz)
    rs += __shfl_xor(rs, 1); rs += __shfl_xor(rs, 2);
    rs += __shfl_xor(rs, 4); rs += __shfl_xor(rs, 8);

    const float bi = p.bias[i];

    // gat_W^T @ gat_a: 8 dot-products of length 64, 64-lane parallel.
    // lane = 8*d + c: dot d (k=d&3, half=d>>2), chunk c covers h=8c..8c+7.
    float s8 = 0.0f;
    {
        const int d8 = lane >> 3, c8 = lane & 7;
        const int kk = d8 & 3;
        const float* ga = p.gat_a + ((d8 < 4) ? 0 : 64);
        #pragma unroll
        for (int h = 0; h < 8; ++h)
            s8 += p.gat_W[kk * 64 + 8 * c8 + h] * ga[8 * c8 + h];
        s8 += __shfl_xor(s8, 1); s8 += __shfl_xor(s8, 2); s8 += __shfl_xor(s8, 4);
    }
    const float w10 = __shfl(s8, 0),  w11 = __shfl(s8, 8);
    const float w12 = __shfl(s8, 16), w13 = __shfl(s8, 24);
    const float w20 = __shfl(s8, 32), w21 = __shfl(s8, 40);
    const float w22 = __shfl(s8, 48), w23 = __shfl(s8, 56);
    const float fd = 16.0f;
    const float f1i = -bi * w10 + bi * w11 + fd * w12 + rs * w13;
    const float f2i = -bi * w20 + bi * w21 + fd * w22 + rs * w23;
    if (t == 0) stA(&p.fA[i], make_float2(f1i, f2i));   // publish EARLY

    // Ci readout MLP (per node, 16 threads per node) — hides fA poll latency
    const int nib = tidb >> 4;
    #pragma unroll
    for (int m = 0; m < 4; ++m) {
        int h = t + 16 * m;
        float a = -bi * p.W1[h] + bi * p.W1[64 + h] + fd * p.W1[128 + h]
                + rs * p.W1[192 + h] + p.b1[h];
        sh1[nib][h] = fmaxf(a, 0.0f);
    }
    __syncthreads();                          // sW2 + sh1 staged
    float civ = 0.0f;
    #pragma unroll
    for (int m = 0; m < 4; ++m) {
        int o = t + 16 * m;
        float acc = p.b2[o];
        for (int h = 0; h < 64; ++h) acc += sh1[nib][h] * sW2[h * 64 + o];
        civ += fmaxf(acc, 0.0f) * p.W3[o];
    }
    civ += __shfl_xor(civ, 1); civ += __shfl_xor(civ, 2);
    civ += __shfl_xor(civ, 4); civ += __shfl_xor(civ, 8);
    const float ci = civ + p.b3[0];

    const float2 fj = pollLd(&p.fA[j]);       // neighbor features (poll)
    float x1 = f1i + fj.y; x1 = (x1 > 0.0f) ? x1 : 0.2f * x1;
    float x2 = fj.x + f2i; x2 = (x2 > 0.0f) ? x2 : 0.2f * x2;
    const float C  = 0.5f * (__expf(x1) + __expf(x2));   // symmetric g <-> rev[g]
    const float js = Jv / C;
    stA(&p.jsC[g], make_float2(js, C));       // for epilogue (foreign reads)

    float sc = C;
    sc += __shfl_xor(sc, 1); sc += __shfl_xor(sc, 2);
    sc += __shfl_xor(sc, 4); sc += __shfl_xor(sc, 8);
    const float s  = ci + sc;
    const float cl = fmaxf(fabsf(s), 0.1f);
    const float d  = (s > 0.0f) ? cl : ((s < 0.0f) ? -cl : 0.0f);
    const float rd = 1.0f / d;
    const float bs = bi * rd;
    if (t == 0) {
        p.ci_out[i] = ci;                     // outputs (plain stores)
        p.dom_out[i] = d;
        stA(&p.uS[i], make_float2(-bs, bs));  // u^0 = bx_scale (em0 = 0)
    }

    // prefetch epilogue indices + jsC (independent of BP steps)
    int eE = 0, eR = 0, eC = 0, eEr = 0;
    float jse = 0.0f, Ce = 0.0f;
    if (g < p.Eu) {
        eE = p.u2e[g]; eR = p.ru[g]; eC = p.cu[g];
        eEr = p.rev[eE];
        const float2 jc = pollLd(&p.jsC[eE]);
        jse = jc.x; Ce = jc.y;
    }

    // ---------------- BP steps: free-running, write-once u per step ---------
    float in0 = 0.0f, in1 = 0.0f;             // msg j->i (slot g)
    float out0 = 0.0f, out1 = 0.0f;           // msg i->j (slot rev[g])
    float ui0 = -bs, ui1 = bs;                // u[i], tracked by every thread
    for (int st = 0; st < NSTEP; ++st) {
        const float2 uj = pollLd(&p.uS[(size_t)st * N + j]);  // self-announcing
        // in_new = F(u_j - out_old)
        const float a0 = uj.x - out0, a1 = uj.y - out1;
        const float t0 = fmaxf( js + a0, -js + a1);
        const float t1 = fmaxf(-js + a0,  js + a1);
        const float ls = lse2(t0, t1);
        const float ni0 = C * (t0 - ls), ni1 = C * (t1 - ls);
        const float pu0 = ui0, pu1 = ui1;     // save for out-message
        const float pi0 = in0, pi1 = in1;
        in0 = ni0; in1 = ni1;

        float nm0 = in0, nm1 = in1;           // node's 16 incoming messages
        nm0 += __shfl_xor(nm0, 1); nm1 += __shfl_xor(nm1, 1);
        nm0 += __shfl_xor(nm0, 2); nm1 += __shfl_xor(nm1, 2);
        nm0 += __shfl_xor(nm0, 4); nm1 += __shfl_xor(nm1, 4);
        nm0 += __shfl_xor(nm0, 8); nm1 += __shfl_xor(nm1, 8);
        ui0 = -bs + nm0 * rd; ui1 = bs + nm1 * rd;
        if (t == 0) stA(&p.uS[(size_t)(st + 1) * N + i], make_float2(ui0, ui1));
        if (st == NSTEP - 1) stA(&p.em[g], make_float2(in0, in1));

        // out_new = F(u_i_old - in_old) — off the inter-node critical path
        const float b0 = pu0 - pi0, b1 = pu1 - pi1;
        const float q0 = fmaxf( js + b0, -js + b1);
        const float q1 = fmaxf(-js + b0,  js + b1);
        const float qs = lse2(q0, q1);
        out0 = C * (q0 - qs); out1 = C * (q1 - qs);
    }

    // ---------------- node readout + node entropy ---------------------------
    float nodeC = 0.0f;
    if (t == 0) {
        const float lz = lse2(ui0, ui1);
        const float r0 = __expf(ui0 - lz), r1 = __expf(ui1 - lz);
        p.ro_out[i] = make_float2(r0, r1);
        const float H = -(r0 * __logf(r0 + 1e-16f) + r1 * __logf(r1 + 1e-16f));
        nodeC = ci * H;
    }
    for (int off = 32; off > 0; off >>= 1) nodeC += __shfl_down(nodeC, off);
    {
        const int wv = tidb >> 6;
        if (lane == 0) red[wv] = nodeC;
        __syncthreads();
        if (tidb == 0) {
            float sn = 0.0f;
            #pragma unroll
            for (int w = 0; w < TB / 64; ++w) sn += red[w];
            atomicAdd(&p.ent[0], sn);
            atomicAdd(&p.ent[1], sn);
        }
        __syncthreads();                      // protect red[] reuse below
    }

    // ---------------- epilogue: ONE batched poll round per upper edge -------
    const float2* uF = p.uS + (size_t)NSTEP * N;
    float edgeC = 0.0f;
    if (g < p.Eu) {
        const float2* A1 = &uF[eC];           // final u at node cu
        const float2* A2 = &uF[eR];           // final u at node ru
        const float2* A3 = &p.em[eEr];        // msg on edge e at slot rev[e]
        const float2* A4 = &p.em[eE];         // msg on rev[e] at slot e
        union { float2 f; unsigned long long u; } a1, a2, a3, a4;
        a1.u = a2.u = a3.u = a4.u = SENTV;
        for (;;) {                            // re-load only pending slots
            if (a1.u == SENTV) a1.u = ldU(A1);
            if (a2.u == SENTV) a2.u = ldU(A2);
            if (a3.u == SENTV) a3.u = ldU(A3);
            if (a4.u == SENTV) a4.u = ldU(A4);
            if (a1.u != SENTV && a2.u != SENTV &&
                a3.u != SENTV && a4.u != SENTV) break;
            __builtin_amdgcn_s_sleep(1);
        }
        const float2 uc = a1.f, ur = a2.f;
        const float2 eme = a3.f;              // ref em[e]      (pairs u_c)
        const float2 emr = a4.f;              // ref em[rev e]  (pairs u_r)
        const float lc = lse2(uc.x, uc.y);
        const float lr = lse2(ur.x, ur.y);
        const float ti0 = (uc.x - lc) - eme.x, ti1 = (uc.y - lc) - eme.y;
        const float tj0 = (ur.x - lr) - emr.x, tj1 = (ur.y - lr) - emr.y;
        const float L00 =  jse + ti0 + tj0;
        const float L01 = -jse + ti1 + tj0;
        const float L10 = -jse + ti0 + tj1;
        const float L11 =  jse + ti1 + tj1;
        const float mL = fmaxf(fmaxf(L00, L01), fmaxf(L10, L11));
        float p00 = __expf(L00 - mL), p01 = __expf(L01 - mL);
        float p10 = __expf(L10 - mL), p11 = __expf(L11 - mL);
        const float inv = 1.0f / (p00 + p01 + p10 + p11);
        p00 *= inv; p01 *= inv; p10 *= inv; p11 *= inv;
        p.rp_out[g] = make_float4(p00, p01, p10, p11);
        p.cij_out[g] = Ce;
        const float H = -(p00 * __logf(p00 + 1e-16f) + p01 * __logf(p01 + 1e-16f)
                        + p10 * __logf(p10 + 1e-16f) + p11 * __logf(p11 + 1e-16f));
        edgeC = Ce * H;
    }
    for (int off = 32; off > 0; off >>= 1) edgeC += __shfl_down(edgeC, off);
    const int wv = tidb >> 6;
    if (lane == 0) red[wv] = edgeC;
    __syncthreads();
    if (tidb == 0) {
        float se = 0.0f;
        #pragma unroll
        for (int w = 0; w < TB / 64; ++w) se += red[w];
        atomicAdd(&p.ent[0], se);
        atomicAdd(&p.ent[2], se);
    }
}

extern "C" void kernel_launch(void* const* d_in, const int* in_sizes, int n_in,
                              void* d_out, int out_size, void* d_ws, size_t ws_size,
                              hipStream_t stream) {
    const int N  = in_sizes[1];
    const int E  = in_sizes[10];
    const int Eu = in_sizes[13];

    float* out = (float*)d_out;
    size_t OFF_RP  = 2 * (size_t)N;
    size_t OFF_ENT = OFF_RP + 4 * (size_t)Eu;

    char* w = (char*)d_ws;
    auto carve = [&](size_t bytes) {
        void* q = (void*)w;
        w += (bytes + 255) & ~(size_t)255;
        return q;
    };

    KParams p;
    p.J     = (const float*)d_in[0];
    p.bias  = (const float*)d_in[1];
    p.gat_W = (const float*)d_in[2];
    p.gat_a = (const float*)d_in[3];
    p.W1    = (const float*)d_in[4];
    p.b1    = (const float*)d_in[5];
    p.W2    = (const float*)d_in[6];
    p.b2    = (const float*)d_in[7];
    p.W3    = (const float*)d_in[8];
    p.b3    = (const float*)d_in[9];
    p.col   = (const int*)d_in[11];
    p.rev   = (const int*)d_in[12];
    p.ru    = (const int*)d_in[13];
    p.cu    = (const int*)d_in[14];
    p.u2e   = (const int*)d_in[15];
    p.N = N; p.Eu = Eu;

    // contiguous sentinel region: fA | jsC | em | uS  (all 256B-multiples)
    const size_t szFA = (size_t)N * 8;                 // 32 KB
    const size_t szJC = (size_t)E * 8;                 // 512 KB
    const size_t szEM = (size_t)E * 8;                 // 512 KB
    const size_t szUS = (size_t)(NSTEP + 1) * N * 8;   // 352 KB
    p.fA  = (float2*)carve(szFA);
    p.jsC = (float2*)carve(szJC);
    p.em  = (float2*)carve(szEM);
    p.uS  = (float2*)carve(szUS);

    p.ro_out  = (float2*)out;
    p.rp_out  = (float4*)(out + OFF_RP);
    p.ent     = out + OFF_ENT;
    p.ci_out  = p.ent + 3;
    p.cij_out = p.ci_out + N;
    p.dom_out = p.cij_out + Eu;

    // one memset: sentinel-fill every cross-block buffer (write-once slots)
    hipMemsetAsync(p.fA, 0xFF, szFA + szJC + szEM + szUS, stream);
    k_fused<<<dim3(NB), dim3(TB), 0, stream>>>(p);
}

// Round 14
// 154.276 us; speedup vs baseline: 1.0879x; 1.0127x over previous
//
#include <hip/hip_runtime.h>
#include <cstddef>

#define TB    512
#define NB    128
#define NSTEP 10
#define SENTV 0xFFFFFFFFFFFFFFFFULL
// Problem constants: N=4096, E=65536 (=N*16, uniform degree 16, row-major
// sorted so out-edges of node i are slots [16i,16i+16)), Eu=32768.
// Slot scheme: em slot g (g=16i+t) holds the message on edge rev[g]=(j->i).
// We propagate u = hidden + lnZ; hidden recovered as u - lse(u) at readout.
// R20 = R19 (156.2us total, best) + tail polish only:
//  (1) epilogue poll ISSUED before the node-entropy block (2 syncthreads +
//      atomics of cover), re-poll only still-sentinel slots after.
//  (2) entropy atomics de-contended: node adds ent[1] only, edge adds ent[2]
//      only; each block vmcnt(0)-drains then bumps a counter; LAST block
//      computes ent[0]=ent[1]+ent[2]. (512 same-line atomics -> 256 on two
//      lines + 128 counter bumps; visibility by drain-at-MALL, as R13.)
//  (3) red[] split into redN/redE -> one fewer __syncthreads.
// R19 recap: R13 self-announcing-data base (write-once sentinel slots,
// consumers poll the datum's own bits != sentinel; no barriers/fences;
// u gets NSTEP+1 buffers, nodes free-run) + 64-lane gatW reduction +
// u-publish-before-out-message + batched epilogue poll.
// Structural floor (documented R20): 10 serial cross-die rounds ~15us +
// setup ~8-10 + launch/memset ~5 + epilogue/tail ~3 => ~31-35us; halo
// replication to cut rounds nets ~0 within LDS/VGPR budgets.

__device__ __forceinline__ float lse2(float a, float b) {
    return fmaxf(a, b) + __logf(1.0f + __expf(-fabsf(a - b)));
}

// agent-scope write-through / cache-bypass 8B accessors
__device__ __forceinline__ void stA(float2* p, float2 v) {
    union { float2 f; unsigned long long u; } x; x.f = v;
    __hip_atomic_store((unsigned long long*)p, x.u,
                       __ATOMIC_RELAXED, __HIP_MEMORY_SCOPE_AGENT);
}
__device__ __forceinline__ unsigned long long ldU(const float2* p) {
    return __hip_atomic_load((const unsigned long long*)p,
                             __ATOMIC_RELAXED, __HIP_MEMORY_SCOPE_AGENT);
}
// poll the datum itself until its bits != sentinel; returns the value
__device__ __forceinline__ float2 pollLd(const float2* p) {
    union { float2 f; unsigned long long u; } x;
    x.u = ldU(p);
    while (x.u == SENTV) {
        __builtin_amdgcn_s_sleep(1);
        x.u = ldU(p);
    }
    return x.f;
}

struct KParams {
    const float *J, *bias, *gat_W, *gat_a, *W1, *b1, *W2, *b2, *W3, *b3;
    const int *col, *rev, *ru, *cu, *u2e;
    int N, Eu;
    float2 *fA, *jsC, *em, *uS;   // uS: (NSTEP+1) x N, all sentinel-init
    int*    cnt;                  // block-completion counter (device-zeroed)
    float  *ci_out, *dom_out, *ent;
    float2* ro_out;
    float4* rp_out;
    float*  cij_out;
};

__global__ __launch_bounds__(TB) void k_fused(KParams p) {
    __shared__ float sW2[64 * 64];
    __shared__ float sh1[TB / 16][65];
    __shared__ float redN[TB / 64];
    __shared__ float redE[TB / 64];

    const int tidb = threadIdx.x;
    const int g = blockIdx.x * TB + tidb;
    const int i = g >> 4, t = g & 15;
    const int lane = tidb & 63;
    const int N = p.N;

    // ---------------- setup ------------------------------------------------
    for (int k = tidb; k < 64 * 64; k += TB) sW2[k] = p.W2[k];
    if (g < 3) {  // zero entropy accumulators early; adds happen >>later
        __hip_atomic_store((int*)&p.ent[g], 0,
                           __ATOMIC_RELAXED, __HIP_MEMORY_SCOPE_AGENT);
    }
    if (g == 3) {
        __hip_atomic_store(p.cnt, 0,
                           __ATOMIC_RELAXED, __HIP_MEMORY_SCOPE_AGENT);
    }

    const int j  = p.col[g];
    const float Jv = p.J[(size_t)i * (size_t)N + (size_t)j];

    float rs = Jv;                            // row-sum of node i (16 nnz)
    rs += __shfl_xor(rs, 1); rs += __shfl_xor(rs, 2);
    rs += __shfl_xor(rs, 4); rs += __shfl_xor(rs, 8);

    const float bi = p.bias[i];

    // gat_W^T @ gat_a: 8 dot-products of length 64, 64-lane parallel.
    float s8 = 0.0f;
    {
        const int d8 = lane >> 3, c8 = lane & 7;
        const int kk = d8 & 3;
        const float* ga = p.gat_a + ((d8 < 4) ? 0 : 64);
        #pragma unroll
        for (int h = 0; h < 8; ++h)
            s8 += p.gat_W[kk * 64 + 8 * c8 + h] * ga[8 * c8 + h];
        s8 += __shfl_xor(s8, 1); s8 += __shfl_xor(s8, 2); s8 += __shfl_xor(s8, 4);
    }
    const float w10 = __shfl(s8, 0),  w11 = __shfl(s8, 8);
    const float w12 = __shfl(s8, 16), w13 = __shfl(s8, 24);
    const float w20 = __shfl(s8, 32), w21 = __shfl(s8, 40);
    const float w22 = __shfl(s8, 48), w23 = __shfl(s8, 56);
    const float fd = 16.0f;
    const float f1i = -bi * w10 + bi * w11 + fd * w12 + rs * w13;
    const float f2i = -bi * w20 + bi * w21 + fd * w22 + rs * w23;
    if (t == 0) stA(&p.fA[i], make_float2(f1i, f2i));   // publish EARLY

    // Ci readout MLP (per node, 16 threads per node) — hides fA poll latency
    const int nib = tidb >> 4;
    #pragma unroll
    for (int m = 0; m < 4; ++m) {
        int h = t + 16 * m;
        float a = -bi * p.W1[h] + bi * p.W1[64 + h] + fd * p.W1[128 + h]
                + rs * p.W1[192 + h] + p.b1[h];
        sh1[nib][h] = fmaxf(a, 0.0f);
    }
    __syncthreads();                          // sW2 + sh1 staged
    float civ = 0.0f;
    #pragma unroll
    for (int m = 0; m < 4; ++m) {
        int o = t + 16 * m;
        float acc = p.b2[o];
        for (int h = 0; h < 64; ++h) acc += sh1[nib][h] * sW2[h * 64 + o];
        civ += fmaxf(acc, 0.0f) * p.W3[o];
    }
    civ += __shfl_xor(civ, 1); civ += __shfl_xor(civ, 2);
    civ += __shfl_xor(civ, 4); civ += __shfl_xor(civ, 8);
    const float ci = civ + p.b3[0];

    const float2 fj = pollLd(&p.fA[j]);       // neighbor features (poll)
    float x1 = f1i + fj.y; x1 = (x1 > 0.0f) ? x1 : 0.2f * x1;
    float x2 = fj.x + f2i; x2 = (x2 > 0.0f) ? x2 : 0.2f * x2;
    const float C  = 0.5f * (__expf(x1) + __expf(x2));   // symmetric g <-> rev[g]
    const float js = Jv / C;
    stA(&p.jsC[g], make_float2(js, C));       // for epilogue (foreign reads)

    float sc = C;
    sc += __shfl_xor(sc, 1); sc += __shfl_xor(sc, 2);
    sc += __shfl_xor(sc, 4); sc += __shfl_xor(sc, 8);
    const float s  = ci + sc;
    const float cl = fmaxf(fabsf(s), 0.1f);
    const float d  = (s > 0.0f) ? cl : ((s < 0.0f) ? -cl : 0.0f);
    const float rd = 1.0f / d;
    const float bs = bi * rd;
    if (t == 0) {
        p.ci_out[i] = ci;                     // outputs (plain stores)
        p.dom_out[i] = d;
        stA(&p.uS[i], make_float2(-bs, bs));  // u^0 = bx_scale (em0 = 0)
    }

    // prefetch epilogue indices + jsC (independent of BP steps)
    int eE = 0, eR = 0, eC = 0, eEr = 0;
    float jse = 0.0f, Ce = 0.0f;
    if (g < p.Eu) {
        eE = p.u2e[g]; eR = p.ru[g]; eC = p.cu[g];
        eEr = p.rev[eE];
        const float2 jc = pollLd(&p.jsC[eE]);
        jse = jc.x; Ce = jc.y;
    }

    // ---------------- BP steps: free-running, write-once u per step ---------
    float in0 = 0.0f, in1 = 0.0f;             // msg j->i (slot g)
    float out0 = 0.0f, out1 = 0.0f;           // msg i->j (slot rev[g])
    float ui0 = -bs, ui1 = bs;                // u[i], tracked by every thread
    for (int st = 0; st < NSTEP; ++st) {
        const float2 uj = pollLd(&p.uS[(size_t)st * N + j]);  // self-announcing
        // in_new = F(u_j - out_old)
        const float a0 = uj.x - out0, a1 = uj.y - out1;
        const float t0 = fmaxf( js + a0, -js + a1);
        const float t1 = fmaxf(-js + a0,  js + a1);
        const float ls = lse2(t0, t1);
        const float ni0 = C * (t0 - ls), ni1 = C * (t1 - ls);
        const float pu0 = ui0, pu1 = ui1;     // save for out-message
        const float pi0 = in0, pi1 = in1;
        in0 = ni0; in1 = ni1;

        float nm0 = in0, nm1 = in1;           // node's 16 incoming messages
        nm0 += __shfl_xor(nm0, 1); nm1 += __shfl_xor(nm1, 1);
        nm0 += __shfl_xor(nm0, 2); nm1 += __shfl_xor(nm1, 2);
        nm0 += __shfl_xor(nm0, 4); nm1 += __shfl_xor(nm1, 4);
        nm0 += __shfl_xor(nm0, 8); nm1 += __shfl_xor(nm1, 8);
        ui0 = -bs + nm0 * rd; ui1 = bs + nm1 * rd;
        if (t == 0) stA(&p.uS[(size_t)(st + 1) * N + i], make_float2(ui0, ui1));
        if (st == NSTEP - 1) stA(&p.em[g], make_float2(in0, in1));

        // out_new = F(u_i_old - in_old) — off the inter-node critical path
        const float b0 = pu0 - pi0, b1 = pu1 - pi1;
        const float q0 = fmaxf( js + b0, -js + b1);
        const float q1 = fmaxf(-js + b0,  js + b1);
        const float qs = lse2(q0, q1);
        out0 = C * (q0 - qs); out1 = C * (q1 - qs);
    }

    // ---------------- issue epilogue polls EARLY (hidden under entropy) -----
    const float2* uF = p.uS + (size_t)NSTEP * N;
    const float2 *A1 = 0, *A2 = 0, *A3 = 0, *A4 = 0;
    union { float2 f; unsigned long long u; } a1, a2, a3, a4;
    a1.u = a2.u = a3.u = a4.u = SENTV;
    if (g < p.Eu) {
        A1 = &uF[eC];                         // final u at node cu
        A2 = &uF[eR];                         // final u at node ru
        A3 = &p.em[eEr];                      // msg on edge e at slot rev[e]
        A4 = &p.em[eE];                       // msg on rev[e] at slot e
        a1.u = ldU(A1); a2.u = ldU(A2);       // first sweep, non-blocking
        a3.u = ldU(A3); a4.u = ldU(A4);
    }

    // ---------------- node readout + node entropy ---------------------------
    float nodeC = 0.0f;
    if (t == 0) {
        const float lz = lse2(ui0, ui1);
        const float r0 = __expf(ui0 - lz), r1 = __expf(ui1 - lz);
        p.ro_out[i] = make_float2(r0, r1);
        const float H = -(r0 * __logf(r0 + 1e-16f) + r1 * __logf(r1 + 1e-16f));
        nodeC = ci * H;
    }
    for (int off = 32; off > 0; off >>= 1) nodeC += __shfl_down(nodeC, off);
    {
        const int wv = tidb >> 6;
        if (lane == 0) redN[wv] = nodeC;
        __syncthreads();
        if (tidb == 0) {
            float sn = 0.0f;
            #pragma unroll
            for (int w = 0; w < TB / 64; ++w) sn += redN[w];
            atomicAdd(&p.ent[1], sn);         // node entropy only
        }
    }

    // ---------------- epilogue: finish batched poll, compute ----------------
    float edgeC = 0.0f;
    if (g < p.Eu) {
        while (a1.u == SENTV || a2.u == SENTV ||
               a3.u == SENTV || a4.u == SENTV) {
            __builtin_amdgcn_s_sleep(1);
            if (a1.u == SENTV) a1.u = ldU(A1);
            if (a2.u == SENTV) a2.u = ldU(A2);
            if (a3.u == SENTV) a3.u = ldU(A3);
            if (a4.u == SENTV) a4.u = ldU(A4);
        }
        const float2 uc = a1.f, ur = a2.f;
        const float2 eme = a3.f;              // ref em[e]      (pairs u_c)
        const float2 emr = a4.f;              // ref em[rev e]  (pairs u_r)
        const float lc = lse2(uc.x, uc.y);
        const float lr = lse2(ur.x, ur.y);
        const float ti0 = (uc.x - lc) - eme.x, ti1 = (uc.y - lc) - eme.y;
        const float tj0 = (ur.x - lr) - emr.x, tj1 = (ur.y - lr) - emr.y;
        const float L00 =  jse + ti0 + tj0;
        const float L01 = -jse + ti1 + tj0;
        const float L10 = -jse + ti0 + tj1;
        const float L11 =  jse + ti1 + tj1;
        const float mL = fmaxf(fmaxf(L00, L01), fmaxf(L10, L11));
        float p00 = __expf(L00 - mL), p01 = __expf(L01 - mL);
        float p10 = __expf(L10 - mL), p11 = __expf(L11 - mL);
        const float inv = 1.0f / (p00 + p01 + p10 + p11);
        p00 *= inv; p01 *= inv; p10 *= inv; p11 *= inv;
        p.rp_out[g] = make_float4(p00, p01, p10, p11);
        p.cij_out[g] = Ce;
        const float H = -(p00 * __logf(p00 + 1e-16f) + p01 * __logf(p01 + 1e-16f)
                        + p10 * __logf(p10 + 1e-16f) + p11 * __logf(p11 + 1e-16f));
        edgeC = Ce * H;
    }
    for (int off = 32; off > 0; off >>= 1) edgeC += __shfl_down(edgeC, off);
    const int wv = tidb >> 6;
    if (lane == 0) redE[wv] = edgeC;
    __syncthreads();
    if (tidb == 0) {
        float se = 0.0f;
        #pragma unroll
        for (int w = 0; w < TB / 64; ++w) se += redE[w];
        atomicAdd(&p.ent[2], se);             // edge entropy only
        // drain my atomics to the coherence point, then announce completion;
        // the LAST block sums ent[0] = ent[1] + ent[2] (all adds performed).
        asm volatile("s_waitcnt vmcnt(0)" ::: "memory");
        const int old = __hip_atomic_fetch_add(p.cnt, 1, __ATOMIC_RELAXED,
                                               __HIP_MEMORY_SCOPE_AGENT);
        if (old == NB - 1) {
            union { float f; int u; } e1, e2, e0;
            e1.u = __hip_atomic_load((int*)&p.ent[1], __ATOMIC_RELAXED,
                                     __HIP_MEMORY_SCOPE_AGENT);
            e2.u = __hip_atomic_load((int*)&p.ent[2], __ATOMIC_RELAXED,
                                     __HIP_MEMORY_SCOPE_AGENT);
            e0.f = e1.f + e2.f;
            __hip_atomic_store((int*)&p.ent[0], e0.u, __ATOMIC_RELAXED,
                               __HIP_MEMORY_SCOPE_AGENT);
        }
    }
}

extern "C" void kernel_launch(void* const* d_in, const int* in_sizes, int n_in,
                              void* d_out, int out_size, void* d_ws, size_t ws_size,
                              hipStream_t stream) {
    const int N  = in_sizes[1];
    const int E  = in_sizes[10];
    const int Eu = in_sizes[13];

    float* out = (float*)d_out;
    size_t OFF_RP  = 2 * (size_t)N;
    size_t OFF_ENT = OFF_RP + 4 * (size_t)Eu;

    char* w = (char*)d_ws;
    auto carve = [&](size_t bytes) {
        void* q = (void*)w;
        w += (bytes + 255) & ~(size_t)255;
        return q;
    };

    KParams p;
    p.J     = (const float*)d_in[0];
    p.bias  = (const float*)d_in[1];
    p.gat_W = (const float*)d_in[2];
    p.gat_a = (const float*)d_in[3];
    p.W1    = (const float*)d_in[4];
    p.b1    = (const float*)d_in[5];
    p.W2    = (const float*)d_in[6];
    p.b2    = (const float*)d_in[7];
    p.W3    = (const float*)d_in[8];
    p.b3    = (const float*)d_in[9];
    p.col   = (const int*)d_in[11];
    p.rev   = (const int*)d_in[12];
    p.ru    = (const int*)d_in[13];
    p.cu    = (const int*)d_in[14];
    p.u2e   = (const int*)d_in[15];
    p.N = N; p.Eu = Eu;

    // contiguous sentinel region: fA | jsC | em | uS  (all 256B-multiples);
    // cnt carved AFTER the region (device-zeroed, not sentinel-filled).
    const size_t szFA = (size_t)N * 8;                 // 32 KB
    const size_t szJC = (size_t)E * 8;                 // 512 KB
    const size_t szEM = (size_t)E * 8;                 // 512 KB
    const size_t szUS = (size_t)(NSTEP + 1) * N * 8;   // 352 KB
    p.fA  = (float2*)carve(szFA);
    p.jsC = (float2*)carve(szJC);
    p.em  = (float2*)carve(szEM);
    p.uS  = (float2*)carve(szUS);
    p.cnt = (int*)carve(256);

    p.ro_out  = (float2*)out;
    p.rp_out  = (float4*)(out + OFF_RP);
    p.ent     = out + OFF_ENT;
    p.ci_out  = p.ent + 3;
    p.cij_out = p.ci_out + N;
    p.dom_out = p.cij_out + Eu;

    // one memset: sentinel-fill every cross-block buffer (write-once slots)
    hipMemsetAsync(p.fA, 0xFF, szFA + szJC + szEM + szUS, stream);
    k_fused<<<dim3(NB), dim3(TB), 0, stream>>>(p);
}